// Round 10
// baseline (47.603 us; speedup 1.0000x reference)
//
#include <hip/hip_runtime.h>

// Steered 3x3 conv as per-pixel GEMM (K=256 = 64ch x 4 feats) via bf16 MFMA.
// v10 = v9 with the weight-indexing bug FIXED: r9 reused r8's per-CHUNK
// offsets (c*2048, A1=+1024; each chunk = 2 K-steps) in a per-KCG loop --
// OOB reads past the 32KB wb array for kcg>=8 (absmax 6.26). Correct:
// kcg*1024, A1 = +256. Tap f32x2 loads declared aligned(4) (w-1 parity is
// arbitrary; don't let codegen assume 8B alignment).
// Regime: NO LDS, NO barriers; 18 VMEM + ~170 VALU per K-step; unroll 2 so
// next iter's independent loads issue under current iter's math.
// B-frag: lane l -> col = l&31 (pixel), k = 16*kc + 8*(l>>5) + r  (verified r2)
// C/D:    col = lane&31, row(o) = (r&3) + 8*(r>>2) + 4*(lane>>5)  (verified r2)

typedef __bf16 bf16x8 __attribute__((ext_vector_type(8)));
typedef float  f32x16 __attribute__((ext_vector_type(16)));
typedef float  f32x2  __attribute__((ext_vector_type(2), aligned(4)));

#define HH 128
#define WW 128
#define HW 16384

// Weights f32[o][k] -> bf16 grouped per MFMA A-fragment (coalesced loads):
// wb[((kcg*2+hx)*64 + o)*8 + r] = bf16(wt[o][kcg*16 + hx*8 + r])
__global__ void wt_repack(const float* __restrict__ wt,
                          unsigned short* __restrict__ wb) {
    int i = blockIdx.x * 256 + threadIdx.x;   // i = o*256 + k
    int o = i >> 8, k = i & 255;
    union { float f; unsigned u; } v; v.f = wt[i];
    unsigned short b = (unsigned short)((v.u + 0x7FFF + ((v.u >> 16) & 1)) >> 16);
    int kcg = k >> 4, hxx = (k >> 3) & 1, r = k & 7;
    wb[((kcg * 2 + hxx) * 64 + o) * 8 + r] = b;
}

__global__ __launch_bounds__(256, 2) void steered_conv(
    const float* __restrict__ x, const float* __restrict__ theta,
    const unsigned short* __restrict__ wb, const float* __restrict__ bias,
    float* __restrict__ out)
{
    const int tid  = threadIdx.x;
    const int wid  = tid >> 6, lane = tid & 63;
    const int pc   = lane & 31, hx = lane >> 5;

    // bijective XCD swizzle: 1024 blocks, 128/XCD = 2 whole images
    const int bb  = blockIdx.x;
    const int swz = (bb & 7) * 128 + (bb >> 3);
    const int n  = swz >> 6;
    const int ty = (swz >> 2) & 15, tx = swz & 3;
    const int hA = ty * 8 + wid * 2;       // this wave's first pixel row
    const int w  = tx * 32 + pc;           // this lane's pixel column

    // ---- per-pixel harmonics for the wave's two rows ----
    float s1a, c1a, s1b, c1b;
    __sincosf(6.2831853071795864769f * theta[(n * HH + hA) * WW + w], &s1a, &c1a);
    __sincosf(6.2831853071795864769f * theta[(n * HH + hA + 1) * WW + w], &s1b, &c1b);
    const float c2a = 2.f * c1a * c1a - 1.f, s2a = 2.f * s1a * c1a;
    const float c2b = 2.f * c1b * c1b - 1.f, s2b = 2.f * s1b * c1b;

    // ---- loop-invariant tap offsets + boundary masks (all in VGPRs) ----
    const bool lv  = (w > 0);
    const int  wL  = lv ? w - 1 : 0;            // dwordx2 base col (L,C)
    const int  wR  = (w < WW - 1) ? w + 1 : WW - 1;
    int   oLC[4], oR[4];
    float mL[4], mC[4], mR[4];
    #pragma unroll
    for (int r = 0; r < 4; ++r) {
        const int gh = hA - 1 + r;
        const bool vr = (unsigned)gh < (unsigned)HH;
        const int ghc = gh < 0 ? 0 : (gh > HH - 1 ? HH - 1 : gh);
        oLC[r] = ghc * WW + wL;
        oR[r]  = ghc * WW + wR;
        mL[r] = (vr && lv) ? 1.f : 0.f;
        mC[r] = vr ? 1.f : 0.f;
        mR[r] = (vr && w < WW - 1) ? 1.f : 0.f;
    }

    f32x16 acc00, acc01, acc10, acc11;
    #pragma unroll
    for (int r = 0; r < 16; ++r) { acc00[r]=0.f; acc01[r]=0.f; acc10[r]=0.f; acc11[r]=0.f; }

    const float RS  = 0.35355339059327373f;   // sqrt(2)/4
    const float HMR = 0.14644660940672627f;   // 0.5 - RS

    // channel base for this lane-half: channels kcg*4 + hx*2 (+1)
    const float* xb = x + (size_t)n * 64 * HW + (size_t)(hx * 2) * HW;
    const unsigned short* wbl = wb + (hx * 64 + pc) * 8;

    #pragma unroll 2
    for (int kcg = 0; kcg < 16; ++kcg) {
        const float* p0 = xb + (size_t)(kcg * 4) * HW;   // uniform (SGPR base)
        const float* p1 = p0 + HW;

        // ---- issue all 18 independent loads up front ----
        f32x2 q0[4], q1[4];
        float r0[4], r1[4];
        #pragma unroll
        for (int r = 0; r < 4; ++r) {
            q0[r] = *(const f32x2*)(p0 + oLC[r]);
            q1[r] = *(const f32x2*)(p1 + oLC[r]);
            r0[r] = p0[oR[r]];
            r1[r] = p1[oR[r]];
        }
        // A-fragment: index = ((kcg*2+hx)*64 + o)*8 + r -> wbl + kcg*1024,
        // o+32 at +256 elements. (r9 bug: used kcg*2048 / +1024 = OOB.)
        const unsigned short* wr = wbl + kcg * 1024;
        const bf16x8 A0 = *(const bf16x8*)wr;
        const bf16x8 A1 = *(const bf16x8*)(wr + 256);

        // ---- per-row primitives S,D,C for the channel pair ----
        f32x2 S[4], D[4], Cv[4];
        #pragma unroll
        for (int r = 0; r < 4; ++r) {
            const float C0 = lv ? q0[r].y : q0[r].x;   // w==0 position shift
            const float C1 = lv ? q1[r].y : q1[r].x;
            const float a0 = mL[r] * q0[r].x, a1 = mL[r] * q1[r].x;
            const float b0v = mC[r] * C0,     b1v = mC[r] * C1;
            const float c0 = mR[r] * r0[r],   c1v = mR[r] * r1[r];
            S[r]  = f32x2{a0 + b0v + c0, a1 + b1v + c1v};
            D[r]  = f32x2{c0 - a0,       c1v - a1};
            Cv[r] = f32x2{b0v,           b1v};
        }

        bf16x8 b0, b1;
        {   // pixel row hA (tap rows 0,1,2)
            f32x2 T  = S[1] - Cv[1];
            f32x2 F1 = RS * (S[0] + S[2] + T);
            f32x2 B2 = RS * (D[0] + D[2]) + 0.5f * D[1];
            f32x2 B3 = RS * (S[2] - S[0]) + HMR * (Cv[2] - Cv[0]);
            f32x2 B4 = 0.5f * (T - (Cv[0] + Cv[2]));
            f32x2 B5 = 0.5f * (D[2] - D[0]);
            f32x2 F2 = c1a * B2 + s1a * B3;
            f32x2 F3 = c2a * B4 + s2a * B5;
            b0[0]=(__bf16)Cv[1].x; b0[1]=(__bf16)F1.x; b0[2]=(__bf16)F2.x; b0[3]=(__bf16)F3.x;
            b0[4]=(__bf16)Cv[1].y; b0[5]=(__bf16)F1.y; b0[6]=(__bf16)F2.y; b0[7]=(__bf16)F3.y;
        }
        {   // pixel row hA+1 (tap rows 1,2,3)
            f32x2 T  = S[2] - Cv[2];
            f32x2 F1 = RS * (S[1] + S[3] + T);
            f32x2 B2 = RS * (D[1] + D[3]) + 0.5f * D[2];
            f32x2 B3 = RS * (S[3] - S[1]) + HMR * (Cv[3] - Cv[1]);
            f32x2 B4 = 0.5f * (T - (Cv[1] + Cv[3]));
            f32x2 B5 = 0.5f * (D[3] - D[1]);
            f32x2 F2 = c1b * B2 + s1b * B3;
            f32x2 F3 = c2b * B4 + s2b * B5;
            b1[0]=(__bf16)Cv[2].x; b1[1]=(__bf16)F1.x; b1[2]=(__bf16)F2.x; b1[3]=(__bf16)F3.x;
            b1[4]=(__bf16)Cv[2].y; b1[5]=(__bf16)F1.y; b1[6]=(__bf16)F2.y; b1[7]=(__bf16)F3.y;
        }

        acc00 = __builtin_amdgcn_mfma_f32_32x32x16_bf16(A0, b0, acc00, 0, 0, 0);
        acc01 = __builtin_amdgcn_mfma_f32_32x32x16_bf16(A1, b0, acc01, 0, 0, 0);
        acc10 = __builtin_amdgcn_mfma_f32_32x32x16_bf16(A0, b1, acc10, 0, 0, 0);
        acc11 = __builtin_amdgcn_mfma_f32_32x32x16_bf16(A1, b1, acc11, 0, 0, 0);
    }

    const size_t hw = (size_t)HW;
    float* op = out + (size_t)n * 64 * hw + (size_t)hA * WW + w;
    #pragma unroll
    for (int r = 0; r < 16; ++r) {
        const int o = (r & 3) + 8 * (r >> 2) + 4 * hx;
        const float bo = bias[o], bo2 = bias[o + 32];
        op[(size_t)o * hw]             = acc00[r] + bo;
        op[(size_t)(o + 32) * hw]      = acc01[r] + bo2;
        op[(size_t)o * hw + WW]        = acc10[r] + bo;
        op[(size_t)(o + 32) * hw + WW] = acc11[r] + bo2;
    }
}

extern "C" void kernel_launch(void* const* d_in, const int* in_sizes, int n_in,
                              void* d_out, int out_size, void* d_ws, size_t ws_size,
                              hipStream_t stream) {
    const float* x     = (const float*)d_in[0];
    const float* theta = (const float*)d_in[1];
    const float* wt    = (const float*)d_in[2];
    const float* bias  = (const float*)d_in[3];
    float* out = (float*)d_out;
    unsigned short* wb = (unsigned short*)d_ws;   // 32 KB bf16 weights (repacked)

    wt_repack<<<64, 256, 0, stream>>>(wt, wb);

    steered_conv<<<1024, 256, 0, stream>>>(x, theta, wb, bias, out);
}